// Round 1
// baseline (562.779 us; speedup 1.0000x reference)
//
#include <hip/hip_runtime.h>

#define N_NODES 100000
#define N_EDGES 1600000
#define INC 128
#define HIDC 128
#define OUTC 64

constexpr int SCAN_CHUNK = 2048;
constexpr int NSB = (N_NODES + SCAN_CHUNK - 1) / SCAN_CHUNK; // 49 blocks

// ---------------- small utility kernels ----------------

__global__ void k_zero(int* __restrict__ p, int n) {
    int i = blockIdx.x * 256 + threadIdx.x;
    if (i < n) p[i] = 0;
}

__global__ void k_count(const int* __restrict__ ei, int* __restrict__ deg) {
    int e = blockIdx.x * 256 + threadIdx.x;
    if (e < N_EDGES) atomicAdd(&deg[ei[N_EDGES + e]], 1);
}

__global__ void k_dinv(const int* __restrict__ deg, float* __restrict__ dinv) {
    int i = blockIdx.x * 256 + threadIdx.x;
    if (i < N_NODES) {
        int d = deg[i];
        dinv[i] = (d > 0) ? rsqrtf((float)d) : 0.f;
    }
}

// ---------------- hierarchical exclusive scan of deg -> offs ----------------

__global__ void k_scan_part(const int* __restrict__ deg, int* __restrict__ bsum) {
    __shared__ int sdata[256];
    int base = blockIdx.x * SCAN_CHUNK;
    int s = 0;
    for (int m = 0; m < SCAN_CHUNK / 256; ++m) {
        int i = base + m * 256 + threadIdx.x;
        s += (i < N_NODES) ? deg[i] : 0;
    }
    sdata[threadIdx.x] = s;
    __syncthreads();
    for (int off = 128; off > 0; off >>= 1) {
        if (threadIdx.x < off) sdata[threadIdx.x] += sdata[threadIdx.x + off];
        __syncthreads();
    }
    if (threadIdx.x == 0) bsum[blockIdx.x] = sdata[0];
}

__global__ void k_scan_top(int* __restrict__ bsum, int* __restrict__ offs) {
    int lane = threadIdx.x; // 0..63, one wave
    int v = (lane < NSB) ? bsum[lane] : 0;
    int x = v;
    for (int off = 1; off < 64; off <<= 1) {
        int t = __shfl_up(x, off);
        if (lane >= off) x += t;
    }
    bsum[lane] = x - v; // exclusive prefix of block sums
    if (lane == 63) offs[N_NODES] = x; // total == E
}

__global__ void k_scan_write(const int* __restrict__ deg, const int* __restrict__ bsum,
                             int* __restrict__ offs, int* __restrict__ cursor) {
    __shared__ int sdata[256];
    const int PT = SCAN_CHUNK / 256; // 8
    int base = blockIdx.x * SCAN_CHUNK;
    int tb = base + threadIdx.x * PT;
    int loc[PT];
    int s = 0;
    for (int m = 0; m < PT; ++m) {
        int i = tb + m;
        int d = (i < N_NODES) ? deg[i] : 0;
        loc[m] = s;
        s += d;
    }
    sdata[threadIdx.x] = s;
    __syncthreads();
    for (int off = 1; off < 256; off <<= 1) {
        int t = (threadIdx.x >= off) ? sdata[threadIdx.x - off] : 0;
        __syncthreads();
        sdata[threadIdx.x] += t;
        __syncthreads();
    }
    int texcl = sdata[threadIdx.x] - s + bsum[blockIdx.x];
    for (int m = 0; m < PT; ++m) {
        int i = tb + m;
        if (i < N_NODES) {
            int o = texcl + loc[m];
            offs[i] = o;
            cursor[i] = o;
        }
    }
}

__global__ void k_place(const int* __restrict__ ei, int* __restrict__ cursor,
                        int* __restrict__ csr_row) {
    int e = blockIdx.x * 256 + threadIdx.x;
    if (e < N_EDGES) {
        int c = ei[N_EDGES + e];
        int p = atomicAdd(&cursor[c], 1);
        csr_row[p] = ei[e];
    }
}

// ---------------- dinv-scaled GEMM: out[n][f] = dinv[n] * sum_k X[n][k]*W[k][f] ----------------
// X: [N][128], W: [128][OUTTOT], tile 64 nodes x 64 outs, K in two halves of 64.
// LDS: xs 64x68 (pad -> conflict-free strided reads), wsh 64x64 (2-way free).

template <int OUTTOT>
__global__ __launch_bounds__(256) void k_gemm_scaled(const float* __restrict__ X,
                                                     const float* __restrict__ W,
                                                     const float* __restrict__ dinv,
                                                     float* __restrict__ out) {
    __shared__ float xs[64][68];
    __shared__ float wsh[64][64];
    const int tid = threadIdx.x;
    const int oq = tid & 15;  // output quad 0..15
    const int nq = tid >> 4;  // node group 0..15
    const int n0 = blockIdx.x * 64;
    const int fo0 = blockIdx.y * 64;
    float acc[4][4] = {};

    for (int kh = 0; kh < 2; ++kh) {
#pragma unroll
        for (int m = 0; m < 4; ++m) {
            int q = tid + 256 * m;
            int row = q >> 4, kq = q & 15;
            int nn = n0 + row;
            float4 v = make_float4(0.f, 0.f, 0.f, 0.f);
            if (nn < N_NODES)
                v = *reinterpret_cast<const float4*>(X + (size_t)nn * 128 + kh * 64 + kq * 4);
            *reinterpret_cast<float4*>(&xs[row][kq * 4]) = v;
        }
#pragma unroll
        for (int m = 0; m < 4; ++m) {
            int q = tid + 256 * m;
            int row = q >> 4, fq = q & 15;
            float4 v = *reinterpret_cast<const float4*>(W + (size_t)(kh * 64 + row) * OUTTOT +
                                                        fo0 + fq * 4);
            *reinterpret_cast<float4*>(&wsh[row][fq * 4]) = v;
        }
        __syncthreads();
#pragma unroll 16
        for (int k = 0; k < 64; ++k) {
            float4 wv = *reinterpret_cast<const float4*>(&wsh[k][oq * 4]);
#pragma unroll
            for (int j = 0; j < 4; ++j) {
                float xv = xs[nq + 16 * j][k];
                acc[j][0] += xv * wv.x;
                acc[j][1] += xv * wv.y;
                acc[j][2] += xv * wv.z;
                acc[j][3] += xv * wv.w;
            }
        }
        __syncthreads();
    }
#pragma unroll
    for (int j = 0; j < 4; ++j) {
        int nn = n0 + nq + 16 * j;
        if (nn < N_NODES) {
            float s = dinv[nn];
            float4 r;
            r.x = acc[j][0] * s;
            r.y = acc[j][1] * s;
            r.z = acc[j][2] * s;
            r.w = acc[j][3] * s;
            *reinterpret_cast<float4*>(out + (size_t)nn * OUTTOT + fo0 + oq * 4) = r;
        }
    }
}

// ---------------- CSR aggregation: out[t] = act(dinv[t]*sum_{r in csr[t]} hs[r] + bias) ----------------

template <int OC, bool RELU>
__global__ __launch_bounds__(OC) void k_agg(const float* __restrict__ hs,
                                            const int* __restrict__ csr_row,
                                            const int* __restrict__ offs,
                                            const float* __restrict__ dinv,
                                            const float* __restrict__ bias,
                                            float* __restrict__ out) {
    const int f = threadIdx.x; // 0..OC-1
    const float bf = bias[f];
    for (int t = blockIdx.x; t < N_NODES; t += gridDim.x) {
        const int s = offs[t], e = offs[t + 1];
        float acc = 0.f;
        for (int j = s; j < e; j += 4) {
            int r0 = csr_row[j];
            int r1 = (j + 1 < e) ? csr_row[j + 1] : -1;
            int r2 = (j + 2 < e) ? csr_row[j + 2] : -1;
            int r3 = (j + 3 < e) ? csr_row[j + 3] : -1;
            float v0 = hs[(size_t)r0 * OC + f];
            float v1 = (r1 >= 0) ? hs[(size_t)r1 * OC + f] : 0.f;
            float v2 = (r2 >= 0) ? hs[(size_t)r2 * OC + f] : 0.f;
            float v3 = (r3 >= 0) ? hs[(size_t)r3 * OC + f] : 0.f;
            acc += v0 + v1 + v2 + v3;
        }
        float r = acc * dinv[t] + bf;
        if (RELU) r = fmaxf(r, 0.f);
        out[(size_t)t * OC + f] = r;
    }
}

// ---------------- launch ----------------

extern "C" void kernel_launch(void* const* d_in, const int* in_sizes, int n_in,
                              void* d_out, int out_size, void* d_ws, size_t ws_size,
                              hipStream_t stream) {
    const float* x  = (const float*)d_in[0];
    const int*   ei = (const int*)d_in[1];   // [2][E] int32 per harness convention
    const float* W1 = (const float*)d_in[2];
    const float* b1 = (const float*)d_in[3];
    const float* W2 = (const float*)d_in[4];
    const float* b2 = (const float*)d_in[5];
    float* out = (float*)d_out;

    char* w = (char*)d_ws;
    auto alloc = [&](size_t bytes) {
        void* p = (void*)w;
        w += (bytes + 255) & ~(size_t)255;
        return p;
    };
    int*   deg     = (int*)alloc((size_t)N_NODES * 4);
    float* dinv    = (float*)alloc((size_t)N_NODES * 4);
    int*   offs    = (int*)alloc((size_t)(N_NODES + 1) * 4);
    int*   cursor  = (int*)alloc((size_t)N_NODES * 4);
    int*   bsum    = (int*)alloc(64 * 4);
    int*   csr_row = (int*)alloc((size_t)N_EDGES * 4);
    float* hs1     = (float*)alloc((size_t)N_NODES * 128 * 4);
    float* h       = (float*)alloc((size_t)N_NODES * 128 * 4);
    float* hs2     = hs1; // reuse: hs1 dead after layer-1 aggregation

    // CSR + norm build
    k_zero<<<(N_NODES + 255) / 256, 256, 0, stream>>>(deg, N_NODES);
    k_count<<<(N_EDGES + 255) / 256, 256, 0, stream>>>(ei, deg);
    k_dinv<<<(N_NODES + 255) / 256, 256, 0, stream>>>(deg, dinv);
    k_scan_part<<<NSB, 256, 0, stream>>>(deg, bsum);
    k_scan_top<<<1, 64, 0, stream>>>(bsum, offs);
    k_scan_write<<<NSB, 256, 0, stream>>>(deg, bsum, offs, cursor);
    k_place<<<(N_EDGES + 255) / 256, 256, 0, stream>>>(ei, cursor, csr_row);

    // layer 1
    dim3 g1((N_NODES + 63) / 64, HIDC / 64);
    k_gemm_scaled<HIDC><<<g1, 256, 0, stream>>>(x, W1, dinv, hs1);
    k_agg<HIDC, true><<<16384, HIDC, 0, stream>>>(hs1, csr_row, offs, dinv, b1, h);

    // layer 2
    dim3 g2((N_NODES + 63) / 64, OUTC / 64);
    k_gemm_scaled<OUTC><<<g2, 256, 0, stream>>>(h, W2, dinv, hs2);
    k_agg<OUTC, false><<<16384, OUTC, 0, stream>>>(hs2, csr_row, offs, dinv, b2, out);
}

// Round 2
// 545.192 us; speedup vs baseline: 1.0323x; 1.0323x over previous
//
#include <hip/hip_runtime.h>

#define N_NODES 100000
#define N_EDGES 1600000
#define INC 128
#define HIDC 128
#define OUTC 64

constexpr int SCAN_CHUNK = 2048;
constexpr int NSB = (N_NODES + SCAN_CHUNK - 1) / SCAN_CHUNK; // 49 blocks
constexpr int NPASS = 8;                                      // one per XCD
constexpr int TRANGE = (N_NODES + NPASS - 1) / NPASS;         // 12500 targets/pass

// ---------------- small utility kernels ----------------

__global__ void k_zero(int* __restrict__ p, int n) {
    int i = blockIdx.x * 256 + threadIdx.x;
    if (i < n) p[i] = 0;
}

// Bucketed degree count: pass p (affinity blockIdx&7 -> XCD p) only touches
// deg lines in its own 50KB window -> atomics stay local to one L2.
__global__ void k_count8(const int* __restrict__ ei, int* __restrict__ deg) {
    const int pass = blockIdx.x & 7;
    const int bid = blockIdx.x >> 3;
    const int nb = gridDim.x >> 3;
    const int lo = pass * TRANGE;
    const int hi = (lo + TRANGE < N_NODES) ? lo + TRANGE : N_NODES;
    for (int e = bid * 256 + threadIdx.x; e < N_EDGES; e += nb * 256) {
        int t = ei[N_EDGES + e];
        if (t >= lo && t < hi) atomicAdd(&deg[t], 1);
    }
}

__global__ void k_dinv(const int* __restrict__ deg, float* __restrict__ dinv) {
    int i = blockIdx.x * 256 + threadIdx.x;
    if (i < N_NODES) {
        int d = deg[i];
        dinv[i] = (d > 0) ? rsqrtf((float)d) : 0.f;
    }
}

// ---------------- hierarchical exclusive scan of deg -> offs ----------------

__global__ void k_scan_part(const int* __restrict__ deg, int* __restrict__ bsum) {
    __shared__ int sdata[256];
    int base = blockIdx.x * SCAN_CHUNK;
    int s = 0;
    for (int m = 0; m < SCAN_CHUNK / 256; ++m) {
        int i = base + m * 256 + threadIdx.x;
        s += (i < N_NODES) ? deg[i] : 0;
    }
    sdata[threadIdx.x] = s;
    __syncthreads();
    for (int off = 128; off > 0; off >>= 1) {
        if (threadIdx.x < off) sdata[threadIdx.x] += sdata[threadIdx.x + off];
        __syncthreads();
    }
    if (threadIdx.x == 0) bsum[blockIdx.x] = sdata[0];
}

__global__ void k_scan_top(int* __restrict__ bsum, int* __restrict__ offs) {
    int lane = threadIdx.x; // 0..63, one wave
    int v = (lane < NSB) ? bsum[lane] : 0;
    int x = v;
    for (int off = 1; off < 64; off <<= 1) {
        int t = __shfl_up(x, off);
        if (lane >= off) x += t;
    }
    bsum[lane] = x - v; // exclusive prefix of block sums
    if (lane == 63) offs[N_NODES] = x; // total == E
}

__global__ void k_scan_write(const int* __restrict__ deg, const int* __restrict__ bsum,
                             int* __restrict__ offs, int* __restrict__ cursor) {
    __shared__ int sdata[256];
    const int PT = SCAN_CHUNK / 256; // 8
    int base = blockIdx.x * SCAN_CHUNK;
    int tb = base + threadIdx.x * PT;
    int loc[PT];
    int s = 0;
    for (int m = 0; m < PT; ++m) {
        int i = tb + m;
        int d = (i < N_NODES) ? deg[i] : 0;
        loc[m] = s;
        s += d;
    }
    sdata[threadIdx.x] = s;
    __syncthreads();
    for (int off = 1; off < 256; off <<= 1) {
        int t = (threadIdx.x >= off) ? sdata[threadIdx.x - off] : 0;
        __syncthreads();
        sdata[threadIdx.x] += t;
        __syncthreads();
    }
    int texcl = sdata[threadIdx.x] - s + bsum[blockIdx.x];
    for (int m = 0; m < PT; ++m) {
        int i = tb + m;
        if (i < N_NODES) {
            int o = texcl + loc[m];
            offs[i] = o;
            cursor[i] = o;
        }
    }
}

// Bucketed CSR placement: pass p only writes csr_row slots for targets in
// [p*TRANGE, (p+1)*TRANGE) -> a ~0.8MB contiguous window owned (via %8 block
// -> XCD round-robin) by one XCD L2, so 64B lines fill before writeback.
__global__ void k_place8(const int* __restrict__ ei, int* __restrict__ cursor,
                         int* __restrict__ csr_row) {
    const int pass = blockIdx.x & 7;
    const int bid = blockIdx.x >> 3;
    const int nb = gridDim.x >> 3;
    const int lo = pass * TRANGE;
    const int hi = (lo + TRANGE < N_NODES) ? lo + TRANGE : N_NODES;
    for (int e = bid * 256 + threadIdx.x; e < N_EDGES; e += nb * 256) {
        int t = ei[N_EDGES + e];
        if (t >= lo && t < hi) {
            int p = atomicAdd(&cursor[t], 1);
            csr_row[p] = ei[e];
        }
    }
}

// ---------------- dinv-scaled GEMM: out[n][f] = dinv[n] * sum_k X[n][k]*W[k][f] ----------------

template <int OUTTOT>
__global__ __launch_bounds__(256) void k_gemm_scaled(const float* __restrict__ X,
                                                     const float* __restrict__ W,
                                                     const float* __restrict__ dinv,
                                                     float* __restrict__ out) {
    __shared__ float xs[64][68];
    __shared__ float wsh[64][64];
    const int tid = threadIdx.x;
    const int oq = tid & 15;  // output quad 0..15
    const int nq = tid >> 4;  // node group 0..15
    const int n0 = blockIdx.x * 64;
    const int fo0 = blockIdx.y * 64;
    float acc[4][4] = {};

    for (int kh = 0; kh < 2; ++kh) {
#pragma unroll
        for (int m = 0; m < 4; ++m) {
            int q = tid + 256 * m;
            int row = q >> 4, kq = q & 15;
            int nn = n0 + row;
            float4 v = make_float4(0.f, 0.f, 0.f, 0.f);
            if (nn < N_NODES)
                v = *reinterpret_cast<const float4*>(X + (size_t)nn * 128 + kh * 64 + kq * 4);
            *reinterpret_cast<float4*>(&xs[row][kq * 4]) = v;
        }
#pragma unroll
        for (int m = 0; m < 4; ++m) {
            int q = tid + 256 * m;
            int row = q >> 4, fq = q & 15;
            float4 v = *reinterpret_cast<const float4*>(W + (size_t)(kh * 64 + row) * OUTTOT +
                                                        fo0 + fq * 4);
            *reinterpret_cast<float4*>(&wsh[row][fq * 4]) = v;
        }
        __syncthreads();
#pragma unroll 16
        for (int k = 0; k < 64; ++k) {
            float4 wv = *reinterpret_cast<const float4*>(&wsh[k][oq * 4]);
#pragma unroll
            for (int j = 0; j < 4; ++j) {
                float xv = xs[nq + 16 * j][k];
                acc[j][0] += xv * wv.x;
                acc[j][1] += xv * wv.y;
                acc[j][2] += xv * wv.z;
                acc[j][3] += xv * wv.w;
            }
        }
        __syncthreads();
    }
#pragma unroll
    for (int j = 0; j < 4; ++j) {
        int nn = n0 + nq + 16 * j;
        if (nn < N_NODES) {
            float s = dinv[nn];
            float4 r;
            r.x = acc[j][0] * s;
            r.y = acc[j][1] * s;
            r.z = acc[j][2] * s;
            r.w = acc[j][3] * s;
            *reinterpret_cast<float4*>(out + (size_t)nn * OUTTOT + fo0 + oq * 4) = r;
        }
    }
}

// ---------------- CSR aggregation ----------------
// Wave-per-(node, 64-feature-slice). 256-thread blocks = 4 independent waves,
// low VGPR, no LDS -> full occupancy for gather-latency hiding. ILP-8 chains.

template <int OC, bool RELU>
__global__ __launch_bounds__(256) void k_agg2(const float* __restrict__ hs,
                                              const int* __restrict__ csr_row,
                                              const int* __restrict__ offs,
                                              const float* __restrict__ dinv,
                                              const float* __restrict__ bias,
                                              float* __restrict__ out) {
    constexpr int SLICES = OC / 64;               // 2 for OC=128, 1 for OC=64
    constexpr int NUNITS = N_NODES * SLICES;
    const int lane = threadIdx.x & 63;
    const int wid = (blockIdx.x * 4) + (threadIdx.x >> 6);
    const int nwaves = gridDim.x * 4;

    for (int u = wid; u < NUNITS; u += nwaves) {
        const int node = (SLICES == 1) ? u : (u >> 1);
        const int f = (SLICES == 1) ? lane : ((u & 1) * 64 + lane);
        const int s = offs[node], e2 = offs[node + 1];
        float acc = 0.f;
        int j = s;
        for (; j + 8 <= e2; j += 8) {
            int r[8];
#pragma unroll
            for (int q = 0; q < 8; ++q) r[q] = csr_row[j + q];
            float v[8];
#pragma unroll
            for (int q = 0; q < 8; ++q) v[q] = hs[(size_t)r[q] * OC + f];
            acc += ((v[0] + v[1]) + (v[2] + v[3])) + ((v[4] + v[5]) + (v[6] + v[7]));
        }
        for (; j < e2; ++j) acc += hs[(size_t)csr_row[j] * OC + f];
        float r = acc * dinv[node] + bias[f];
        if (RELU) r = fmaxf(r, 0.f);
        out[(size_t)node * OC + f] = r;
    }
}

// ---------------- launch ----------------

extern "C" void kernel_launch(void* const* d_in, const int* in_sizes, int n_in,
                              void* d_out, int out_size, void* d_ws, size_t ws_size,
                              hipStream_t stream) {
    const float* x  = (const float*)d_in[0];
    const int*   ei = (const int*)d_in[1];
    const float* W1 = (const float*)d_in[2];
    const float* b1 = (const float*)d_in[3];
    const float* W2 = (const float*)d_in[4];
    const float* b2 = (const float*)d_in[5];
    float* out = (float*)d_out;

    char* w = (char*)d_ws;
    auto alloc = [&](size_t bytes) {
        void* p = (void*)w;
        w += (bytes + 255) & ~(size_t)255;
        return p;
    };
    int*   deg     = (int*)alloc((size_t)N_NODES * 4);
    float* dinv    = (float*)alloc((size_t)N_NODES * 4);
    int*   offs    = (int*)alloc((size_t)(N_NODES + 1) * 4);
    int*   cursor  = (int*)alloc((size_t)N_NODES * 4);
    int*   bsum    = (int*)alloc(64 * 4);
    int*   csr_row = (int*)alloc((size_t)N_EDGES * 4);
    float* hs1     = (float*)alloc((size_t)N_NODES * 128 * 4);
    float* h       = (float*)alloc((size_t)N_NODES * 128 * 4);
    float* hs2     = hs1; // reuse: hs1 dead after layer-1 aggregation

    // CSR + norm build
    k_zero<<<(N_NODES + 255) / 256, 256, 0, stream>>>(deg, N_NODES);
    k_count8<<<3072, 256, 0, stream>>>(ei, deg);
    k_dinv<<<(N_NODES + 255) / 256, 256, 0, stream>>>(deg, dinv);
    k_scan_part<<<NSB, 256, 0, stream>>>(deg, bsum);
    k_scan_top<<<1, 64, 0, stream>>>(bsum, offs);
    k_scan_write<<<NSB, 256, 0, stream>>>(deg, bsum, offs, cursor);
    k_place8<<<3072, 256, 0, stream>>>(ei, cursor, csr_row);

    // layer 1
    dim3 g1((N_NODES + 63) / 64, HIDC / 64);
    k_gemm_scaled<HIDC><<<g1, 256, 0, stream>>>(x, W1, dinv, hs1);
    k_agg2<HIDC, true><<<2048, 256, 0, stream>>>(hs1, csr_row, offs, dinv, b1, h);

    // layer 2
    dim3 g2((N_NODES + 63) / 64, OUTC / 64);
    k_gemm_scaled<OUTC><<<g2, 256, 0, stream>>>(h, W2, dinv, hs2);
    k_agg2<OUTC, false><<<2048, 256, 0, stream>>>(hs2, csr_row, offs, dinv, b2, out);
}

// Round 3
// 444.267 us; speedup vs baseline: 1.2668x; 1.2272x over previous
//
#include <hip/hip_runtime.h>

#define N_NODES 100000
#define N_EDGES 1600000
#define INC 128
#define HIDC 128
#define OUTC 64

constexpr int SCAN_CHUNK = 2048;
constexpr int NSB = (N_NODES + SCAN_CHUNK - 1) / SCAN_CHUNK; // 49 blocks
constexpr int NPASS = 8;                                      // one per XCD
constexpr int TRANGE = (N_NODES + NPASS - 1) / NPASS;         // 12500 targets/pass

// ---------------- bf16 helpers ----------------

__device__ __forceinline__ float blo(unsigned u) { return __uint_as_float(u << 16); }
__device__ __forceinline__ float bhi(unsigned u) { return __uint_as_float(u & 0xFFFF0000u); }
__device__ __forceinline__ unsigned pack_bf2(float a, float b) {
    unsigned ua = __float_as_uint(a);
    ua = (ua + 0x7FFFu + ((ua >> 16) & 1u)) >> 16;
    unsigned ub = __float_as_uint(b);
    ub = (ub + 0x7FFFu + ((ub >> 16) & 1u)) >> 16;
    return ua | (ub << 16);
}

// ---------------- small utility kernels ----------------

__global__ void k_zero(int* __restrict__ p, int n) {
    int i = blockIdx.x * 256 + threadIdx.x;
    if (i < n) p[i] = 0;
}

__global__ void k_count8(const int* __restrict__ ei, int* __restrict__ deg) {
    const int pass = blockIdx.x & 7;
    const int bid = blockIdx.x >> 3;
    const int nb = gridDim.x >> 3;
    const int lo = pass * TRANGE;
    const int hi = (lo + TRANGE < N_NODES) ? lo + TRANGE : N_NODES;
    for (int e = bid * 256 + threadIdx.x; e < N_EDGES; e += nb * 256) {
        int t = ei[N_EDGES + e];
        if (t >= lo && t < hi) atomicAdd(&deg[t], 1);
    }
}

__global__ void k_dinv(const int* __restrict__ deg, float* __restrict__ dinv) {
    int i = blockIdx.x * 256 + threadIdx.x;
    if (i < N_NODES) {
        int d = deg[i];
        dinv[i] = (d > 0) ? rsqrtf((float)d) : 0.f;
    }
}

// ---------------- hierarchical exclusive scan of deg -> offs ----------------

__global__ void k_scan_part(const int* __restrict__ deg, int* __restrict__ bsum) {
    __shared__ int sdata[256];
    int base = blockIdx.x * SCAN_CHUNK;
    int s = 0;
    for (int m = 0; m < SCAN_CHUNK / 256; ++m) {
        int i = base + m * 256 + threadIdx.x;
        s += (i < N_NODES) ? deg[i] : 0;
    }
    sdata[threadIdx.x] = s;
    __syncthreads();
    for (int off = 128; off > 0; off >>= 1) {
        if (threadIdx.x < off) sdata[threadIdx.x] += sdata[threadIdx.x + off];
        __syncthreads();
    }
    if (threadIdx.x == 0) bsum[blockIdx.x] = sdata[0];
}

__global__ void k_scan_top(int* __restrict__ bsum, int* __restrict__ offs) {
    int lane = threadIdx.x; // 0..63, one wave
    int v = (lane < NSB) ? bsum[lane] : 0;
    int x = v;
    for (int off = 1; off < 64; off <<= 1) {
        int t = __shfl_up(x, off);
        if (lane >= off) x += t;
    }
    bsum[lane] = x - v;
    if (lane == 63) offs[N_NODES] = x;
}

__global__ void k_scan_write(const int* __restrict__ deg, const int* __restrict__ bsum,
                             int* __restrict__ offs, int* __restrict__ cursor) {
    __shared__ int sdata[256];
    const int PT = SCAN_CHUNK / 256; // 8
    int base = blockIdx.x * SCAN_CHUNK;
    int tb = base + threadIdx.x * PT;
    int loc[PT];
    int s = 0;
    for (int m = 0; m < PT; ++m) {
        int i = tb + m;
        int d = (i < N_NODES) ? deg[i] : 0;
        loc[m] = s;
        s += d;
    }
    sdata[threadIdx.x] = s;
    __syncthreads();
    for (int off = 1; off < 256; off <<= 1) {
        int t = (threadIdx.x >= off) ? sdata[threadIdx.x - off] : 0;
        __syncthreads();
        sdata[threadIdx.x] += t;
        __syncthreads();
    }
    int texcl = sdata[threadIdx.x] - s + bsum[blockIdx.x];
    for (int m = 0; m < PT; ++m) {
        int i = tb + m;
        if (i < N_NODES) {
            int o = texcl + loc[m];
            offs[i] = o;
            cursor[i] = o;
        }
    }
}

__global__ void k_place8(const int* __restrict__ ei, int* __restrict__ cursor,
                         int* __restrict__ csr_row) {
    const int pass = blockIdx.x & 7;
    const int bid = blockIdx.x >> 3;
    const int nb = gridDim.x >> 3;
    const int lo = pass * TRANGE;
    const int hi = (lo + TRANGE < N_NODES) ? lo + TRANGE : N_NODES;
    for (int e = bid * 256 + threadIdx.x; e < N_EDGES; e += nb * 256) {
        int t = ei[N_EDGES + e];
        if (t >= lo && t < hi) {
            int p = atomicAdd(&cursor[t], 1);
            csr_row[p] = ei[e];
        }
    }
}

// ---------------- dinv-scaled GEMM -> bf16 output ----------------
// hs[n][f] = bf16( dinv[n] * sum_k X[n][k]*W[k][f] )

template <int OUTTOT>
__global__ __launch_bounds__(256) void k_gemm_scaled(const float* __restrict__ X,
                                                     const float* __restrict__ W,
                                                     const float* __restrict__ dinv,
                                                     unsigned short* __restrict__ outb) {
    __shared__ float xs[64][68];
    __shared__ float wsh[64][64];
    const int tid = threadIdx.x;
    const int oq = tid & 15;
    const int nq = tid >> 4;
    const int n0 = blockIdx.x * 64;
    const int fo0 = blockIdx.y * 64;
    float acc[4][4] = {};

    for (int kh = 0; kh < 2; ++kh) {
#pragma unroll
        for (int m = 0; m < 4; ++m) {
            int q = tid + 256 * m;
            int row = q >> 4, kq = q & 15;
            int nn = n0 + row;
            float4 v = make_float4(0.f, 0.f, 0.f, 0.f);
            if (nn < N_NODES)
                v = *reinterpret_cast<const float4*>(X + (size_t)nn * 128 + kh * 64 + kq * 4);
            *reinterpret_cast<float4*>(&xs[row][kq * 4]) = v;
        }
#pragma unroll
        for (int m = 0; m < 4; ++m) {
            int q = tid + 256 * m;
            int row = q >> 4, fq = q & 15;
            float4 v = *reinterpret_cast<const float4*>(W + (size_t)(kh * 64 + row) * OUTTOT +
                                                        fo0 + fq * 4);
            *reinterpret_cast<float4*>(&wsh[row][fq * 4]) = v;
        }
        __syncthreads();
#pragma unroll 16
        for (int k = 0; k < 64; ++k) {
            float4 wv = *reinterpret_cast<const float4*>(&wsh[k][oq * 4]);
#pragma unroll
            for (int j = 0; j < 4; ++j) {
                float xv = xs[nq + 16 * j][k];
                acc[j][0] += xv * wv.x;
                acc[j][1] += xv * wv.y;
                acc[j][2] += xv * wv.z;
                acc[j][3] += xv * wv.w;
            }
        }
        __syncthreads();
    }
#pragma unroll
    for (int j = 0; j < 4; ++j) {
        int nn = n0 + nq + 16 * j;
        if (nn < N_NODES) {
            float s = dinv[nn];
            uint2 pk;
            pk.x = pack_bf2(acc[j][0] * s, acc[j][1] * s);
            pk.y = pack_bf2(acc[j][2] * s, acc[j][3] * s);
            *reinterpret_cast<uint2*>(outb + (size_t)nn * OUTTOT + fo0 + oq * 4) = pk;
        }
    }
}

// ---------------- CSR aggregation over bf16 rows ----------------
// One wave per node. Row = OC bf16 = OC*2 bytes. LPR lanes cover the row with
// 16B uint4 loads; 64/LPR edge slots in parallel; unroll-2 -> 2 loads in
// flight per lane. Cross-slot shfl_xor reduction, fp32 output (bias/relu).

template <int OC, bool RELU>
__global__ __launch_bounds__(256) void k_aggv(const uint4* __restrict__ hs,
                                              const int* __restrict__ csr_row,
                                              const int* __restrict__ offs,
                                              const float* __restrict__ dinv,
                                              const float* __restrict__ bias,
                                              float* __restrict__ out) {
    constexpr int LPR = (OC * 2) / 16;   // 16 (OC=128) or 8 (OC=64)
    constexpr int SLOTS = 64 / LPR;      // 4 or 8
    const int lane = threadIdx.x & 63;
    const int sub = lane / LPR;
    const int q = lane % LPR;
    const int wid = (blockIdx.x * 4) + (threadIdx.x >> 6);
    const int nwaves = gridDim.x * 4;

    for (int t = wid; t < N_NODES; t += nwaves) {
        const int s = offs[t], e2 = offs[t + 1];
        float acc[8] = {0.f, 0.f, 0.f, 0.f, 0.f, 0.f, 0.f, 0.f};
        for (int j = s; j < e2; j += 2 * SLOTS) {
            const int j0 = j + sub, j1 = j + SLOTS + sub;
            const int r0 = (j0 < e2) ? csr_row[j0] : -1;
            const int r1 = (j1 < e2) ? csr_row[j1] : -1;
            uint4 v0 = make_uint4(0u, 0u, 0u, 0u), v1 = v0;
            if (r0 >= 0) v0 = hs[(size_t)r0 * LPR + q];
            if (r1 >= 0) v1 = hs[(size_t)r1 * LPR + q];
            acc[0] += blo(v0.x) + blo(v1.x);
            acc[1] += bhi(v0.x) + bhi(v1.x);
            acc[2] += blo(v0.y) + blo(v1.y);
            acc[3] += bhi(v0.y) + bhi(v1.y);
            acc[4] += blo(v0.z) + blo(v1.z);
            acc[5] += bhi(v0.z) + bhi(v1.z);
            acc[6] += blo(v0.w) + blo(v1.w);
            acc[7] += bhi(v0.w) + bhi(v1.w);
        }
#pragma unroll
        for (int off = 32; off >= LPR; off >>= 1) {
#pragma unroll
            for (int i = 0; i < 8; ++i) acc[i] += __shfl_xor(acc[i], off);
        }
        if (lane < LPR) {
            const float dt = dinv[t];
            const float4 b0 = *reinterpret_cast<const float4*>(bias + lane * 8);
            const float4 b1 = *reinterpret_cast<const float4*>(bias + lane * 8 + 4);
            float4 r0, r1;
            r0.x = acc[0] * dt + b0.x;
            r0.y = acc[1] * dt + b0.y;
            r0.z = acc[2] * dt + b0.z;
            r0.w = acc[3] * dt + b0.w;
            r1.x = acc[4] * dt + b1.x;
            r1.y = acc[5] * dt + b1.y;
            r1.z = acc[6] * dt + b1.z;
            r1.w = acc[7] * dt + b1.w;
            if (RELU) {
                r0.x = fmaxf(r0.x, 0.f); r0.y = fmaxf(r0.y, 0.f);
                r0.z = fmaxf(r0.z, 0.f); r0.w = fmaxf(r0.w, 0.f);
                r1.x = fmaxf(r1.x, 0.f); r1.y = fmaxf(r1.y, 0.f);
                r1.z = fmaxf(r1.z, 0.f); r1.w = fmaxf(r1.w, 0.f);
            }
            float* po = out + (size_t)t * OC + lane * 8;
            *reinterpret_cast<float4*>(po) = r0;
            *reinterpret_cast<float4*>(po + 4) = r1;
        }
    }
}

// ---------------- launch ----------------

extern "C" void kernel_launch(void* const* d_in, const int* in_sizes, int n_in,
                              void* d_out, int out_size, void* d_ws, size_t ws_size,
                              hipStream_t stream) {
    const float* x  = (const float*)d_in[0];
    const int*   ei = (const int*)d_in[1];
    const float* W1 = (const float*)d_in[2];
    const float* b1 = (const float*)d_in[3];
    const float* W2 = (const float*)d_in[4];
    const float* b2 = (const float*)d_in[5];
    float* out = (float*)d_out;

    char* w = (char*)d_ws;
    auto alloc = [&](size_t bytes) {
        void* p = (void*)w;
        w += (bytes + 255) & ~(size_t)255;
        return p;
    };
    int*   deg     = (int*)alloc((size_t)N_NODES * 4);
    float* dinv    = (float*)alloc((size_t)N_NODES * 4);
    int*   offs    = (int*)alloc((size_t)(N_NODES + 1) * 4);
    int*   cursor  = (int*)alloc((size_t)N_NODES * 4);
    int*   bsum    = (int*)alloc(64 * 4);
    int*   csr_row = (int*)alloc((size_t)N_EDGES * 4);
    unsigned short* hs1 = (unsigned short*)alloc((size_t)N_NODES * HIDC * 2); // bf16
    float* h       = (float*)alloc((size_t)N_NODES * HIDC * 4);
    unsigned short* hs2 = hs1; // bf16, reuse (hs1 dead after layer-1 agg)

    // CSR + norm build
    k_zero<<<(N_NODES + 255) / 256, 256, 0, stream>>>(deg, N_NODES);
    k_count8<<<3072, 256, 0, stream>>>(ei, deg);
    k_dinv<<<(N_NODES + 255) / 256, 256, 0, stream>>>(deg, dinv);
    k_scan_part<<<NSB, 256, 0, stream>>>(deg, bsum);
    k_scan_top<<<1, 64, 0, stream>>>(bsum, offs);
    k_scan_write<<<NSB, 256, 0, stream>>>(deg, bsum, offs, cursor);
    k_place8<<<3072, 256, 0, stream>>>(ei, cursor, csr_row);

    // layer 1
    dim3 g1((N_NODES + 63) / 64, HIDC / 64);
    k_gemm_scaled<HIDC><<<g1, 256, 0, stream>>>(x, W1, dinv, hs1);
    k_aggv<HIDC, true><<<2048, 256, 0, stream>>>((const uint4*)hs1, csr_row, offs, dinv, b1, h);

    // layer 2
    dim3 g2((N_NODES + 63) / 64, OUTC / 64);
    k_gemm_scaled<OUTC><<<g2, 256, 0, stream>>>(h, W2, dinv, hs2);
    k_aggv<OUTC, false><<<2048, 256, 0, stream>>>((const uint4*)hs2, csr_row, offs, dinv, b2, out);
}